// Round 1
// baseline (151.574 us; speedup 1.0000x reference)
//
#include <hip/hip_runtime.h>
#include <math.h>

#define NN 1024   // nodes
#define KK 256    // in/out features (both 256)
#define NH 4      // heads
#define FD 64     // n_hidden
#define HF 256    // NH*FD

// ---------------- GEMM: G = A(1024x256) @ W(256x256) ----------------
// z=0: g_l = h @ w_l ; z=1: g_r = nei @ w_r
// tile M=32 x N=64, 256 threads, 2x4 outputs/thread
__global__ __launch_bounds__(256) void gatv2_gemm(
    const float* __restrict__ h, const float* __restrict__ nei,
    const float* __restrict__ w_l, const float* __restrict__ w_r,
    float* __restrict__ g_l, float* __restrict__ g_r)
{
    const float* A; const float* W; float* G;
    if (blockIdx.z == 0) { A = h;   W = w_l; G = g_l; }
    else                 { A = nei; W = w_r; G = g_r; }

    __shared__ float sA[32][36];   // +4 pad: conflict-free a-reads, 16B-aligned writes
    __shared__ float sW[32][64];

    const int t  = threadIdx.x;
    const int tn = t & 15;         // n group (4 cols)
    const int tm = t >> 4;         // m group (2 rows)
    const int n0 = blockIdx.x * 64;
    const int m0 = blockIdx.y * 32;

    float acc0[4] = {0,0,0,0}, acc1[4] = {0,0,0,0};

    for (int kc = 0; kc < KK; kc += 32) {
        const int ar = t >> 3, ac = (t & 7) << 2;
        float4 va = *(const float4*)&A[(size_t)(m0 + ar)*KK + kc + ac];
        const int wc = (t & 15) << 2, wr = t >> 4;
        float4 v0 = *(const float4*)&W[(size_t)(kc + wr)*HF + n0 + wc];
        float4 v1 = *(const float4*)&W[(size_t)(kc + wr + 16)*HF + n0 + wc];
        __syncthreads();
        *(float4*)&sA[ar][ac]    = va;
        *(float4*)&sW[wr][wc]    = v0;
        *(float4*)&sW[wr+16][wc] = v1;
        __syncthreads();
        #pragma unroll
        for (int k = 0; k < 32; ++k) {
            float a0 = sA[tm*2][k];
            float a1 = sA[tm*2+1][k];
            float4 w4 = *(const float4*)&sW[k][tn<<2];
            acc0[0] += a0*w4.x; acc0[1] += a0*w4.y; acc0[2] += a0*w4.z; acc0[3] += a0*w4.w;
            acc1[0] += a1*w4.x; acc1[1] += a1*w4.y; acc1[2] += a1*w4.z; acc1[3] += a1*w4.w;
        }
    }
    const int m = m0 + tm*2, n = n0 + (tn<<2);
    *(float4*)&G[(size_t)m*HF + n]     = make_float4(acc0[0],acc0[1],acc0[2],acc0[3]);
    *(float4*)&G[(size_t)(m+1)*HF + n] = make_float4(acc1[0],acc1[1],acc1[2],acc1[3]);
}

// ---------------- Main attention kernel ----------------
// grid: (NC j-chunks, 4 i-blocks of 256, 4 heads). Thread owns one i.
// e[i,j] = cr[i] + cl[j] + sum_f (0.4*w[f]) * |g_r[i,f] + g_l[j,f]|   (lrelu = 0.6x + 0.4|x|)
// p = adj[j,i] ? exp(e) : 0 ;  partial denom[i] += p ; partial acc[i,f] += p*g_r[j,f]
__global__ __launch_bounds__(256, 2) void gatv2_attn(
    const float* __restrict__ g_l, const float* __restrict__ g_r,
    const float* __restrict__ adj, const float* __restrict__ attn_w,
    float* __restrict__ accP, float* __restrict__ denP,
    int JPB, int SC)
{
    extern __shared__ float sh[];
    float* s_gl = sh;               // [SC][FD]
    float* s_gr = sh + SC*FD;       // [SC][FD]
    float* s_cl = sh + 2*SC*FD;     // [SC]

    const int t     = threadIdx.x;
    const int jcIdx = blockIdx.x;
    const int ib    = blockIdx.y;
    const int hh    = blockIdx.z;
    const int i     = ib*256 + t;

    // wa = 0.4 * attn_w (broadcast loads, lives in VGPRs)
    float4 wa[16];
    {
        const float4* wp = (const float4*)attn_w;
        #pragma unroll
        for (int q = 0; q < 16; ++q) {
            float4 w = wp[q];
            wa[q] = make_float4(w.x*0.4f, w.y*0.4f, w.z*0.4f, w.w*0.4f);
        }
    }
    // own g_r[i] row + cr[i] = 0.6*dot(w, g_r[i]) = 1.5*dot(wa, g_r[i])
    float4 gri[16];
    float cr = 0.f;
    {
        const float4* gp = (const float4*)(g_r + (size_t)i*HF + hh*FD);
        #pragma unroll
        for (int q = 0; q < 16; ++q) {
            gri[q] = gp[q];
            cr += wa[q].x*gri[q].x + wa[q].y*gri[q].y + wa[q].z*gri[q].z + wa[q].w*gri[q].w;
        }
        cr *= 1.5f;
    }
    float4 acc[16];
    #pragma unroll
    for (int q = 0; q < 16; ++q) acc[q] = make_float4(0.f,0.f,0.f,0.f);
    float denom = 0.f;

    const int jbase = jcIdx * JPB;
    for (int s0 = 0; s0 < JPB; s0 += SC) {
        const int j0 = jbase + s0;
        __syncthreads();   // protect LDS from previous sub-chunk readers
        for (int p = t; p < SC*16; p += 256) {
            const int jr = p >> 4, c = (p & 15) << 2;
            *(float4*)&s_gl[jr*FD + c] = *(const float4*)&g_l[(size_t)(j0 + jr)*HF + hh*FD + c];
            *(float4*)&s_gr[jr*FD + c] = *(const float4*)&g_r[(size_t)(j0 + jr)*HF + hh*FD + c];
        }
        __syncthreads();
        if (t < SC) {   // cl[j] = 1.5*dot(wa, g_l[j])
            float s = 0.f;
            const float* row = &s_gl[t*FD];
            #pragma unroll
            for (int q = 0; q < 16; ++q)
                s += wa[q].x*row[4*q] + wa[q].y*row[4*q+1] + wa[q].z*row[4*q+2] + wa[q].w*row[4*q+3];
            s_cl[t] = 1.5f*s;
        }
        __syncthreads();

        float mask_next = adj[(size_t)j0*NN + i];
        for (int jj = 0; jj < SC; ++jj) {
            const float mask = mask_next;
            if (jj + 1 < SC) mask_next = adj[(size_t)(j0 + jj + 1)*NN + i];
            const float clj = s_cl[jj];
            const float4* glr = (const float4*)&s_gl[jj*FD];
            float e0 = 0.f, e1 = 0.f, e2 = 0.f, e3 = 0.f;
            #pragma unroll
            for (int q = 0; q < 16; ++q) {   // 2 VALU per f: v_add + v_fma(abs)
                float4 g = glr[q];
                e0 += wa[q].x * fabsf(g.x + gri[q].x);
                e1 += wa[q].y * fabsf(g.y + gri[q].y);
                e2 += wa[q].z * fabsf(g.z + gri[q].z);
                e3 += wa[q].w * fabsf(g.w + gri[q].w);
            }
            const float e = cr + clj + ((e0+e1)+(e2+e3));
            const float pw = (mask != 0.f) ? __expf(e) : 0.f;
            denom += pw;
            const float4* grr = (const float4*)&s_gr[jj*FD];
            #pragma unroll
            for (int q = 0; q < 16; ++q) {
                float4 g = grr[q];
                acc[q].x += pw*g.x; acc[q].y += pw*g.y;
                acc[q].z += pw*g.z; acc[q].w += pw*g.w;
            }
        }
    }
    float* op = accP + (size_t)jcIdx*(NN*HF) + ((size_t)i*NH + hh)*FD;
    #pragma unroll
    for (int q = 0; q < 16; ++q) ((float4*)op)[q] = acc[q];
    denP[(size_t)jcIdx*(NN*NH) + (size_t)i*NH + hh] = denom;
}

// ---------------- Reduce partials + elu ----------------
__global__ __launch_bounds__(256) void gatv2_reduce(
    const float* __restrict__ accP, const float* __restrict__ denP,
    const int* __restrict__ use_elu, float* __restrict__ out, int NC)
{
    const int idx = blockIdx.x*256 + threadIdx.x;   // (i*NH + h)*FD + f
    float s = 0.f, d = 0.f;
    for (int c = 0; c < NC; ++c) {
        s += accP[(size_t)c*(NN*HF) + idx];
        d += denP[(size_t)c*(NN*NH) + (idx >> 6)];
    }
    float r = s / d;
    if (*use_elu != 0) r = (r > 0.f) ? r : expm1f(r);
    out[idx] = r;
}

extern "C" void kernel_launch(void* const* d_in, const int* in_sizes, int n_in,
                              void* d_out, int out_size, void* d_ws, size_t ws_size,
                              hipStream_t stream)
{
    const float* h    = (const float*)d_in[0];
    const float* nei  = (const float*)d_in[1];
    const float* adj  = (const float*)d_in[2];
    const float* w_l  = (const float*)d_in[3];
    const float* w_r  = (const float*)d_in[4];
    const float* aw   = (const float*)d_in[5];
    const int*   uel  = (const int*)d_in[6];
    float* out = (float*)d_out;
    float* ws  = (float*)d_ws;

    float* g_l = ws;
    float* g_r = ws + (size_t)NN*HF;

    // pick j-chunk count by workspace capacity (NC=32 needs ~36 MB)
    int NC = 32;
    while (NC > 1) {
        size_t need = ((size_t)2*NN*HF + (size_t)NC*NN*NH + (size_t)NC*NN*HF) * sizeof(float);
        if (need <= ws_size) break;
        NC >>= 1;
    }
    const int JPB = NN / NC;
    const int SC  = JPB < 64 ? JPB : 64;

    float* denP = g_r + (size_t)NN*HF;
    float* accP = denP + (size_t)NC*NN*NH;

    hipLaunchKernelGGL(gatv2_gemm, dim3(HF/64, NN/32, 2), dim3(256), 0, stream,
                       h, nei, w_l, w_r, g_l, g_r);
    const size_t shb = (size_t)(2*SC*FD + SC) * sizeof(float);
    hipLaunchKernelGGL(gatv2_attn, dim3(NC, NN/256, NH), dim3(256), shb, stream,
                       g_l, g_r, adj, aw, accP, denP, JPB, SC);
    hipLaunchKernelGGL(gatv2_reduce, dim3((NN*HF)/256), dim3(256), 0, stream,
                       accP, denP, uel, out, NC);
}